// Round 6
// baseline (270.089 us; speedup 1.0000x reference)
//
#include <hip/hip_runtime.h>
#include <hip/hip_bf16.h>
#include <hip/hip_fp16.h>
#include <math.h>

// ---------------------------------------------------------------------------
// DynamicGCN: 3x (GCNConv -> ReLU -> *gate)
// R1: multi-block scan, hist fused into convert, dinv folded into scan C.
// R2: split-bf16 MFMA GEMM, W pre-swizzled into B-fragment order.
// R9: layer outputs stored as PRE-SPLIT bf16 hi/lo planes for layers 1/2.
// R10: agg CSR padded to x4 (tail-free loop); self-edge folded into agg.
// R11: Wf staged per-kc into LDS (double-buffered); X loads global->reg.
// R12: bucket is throughput-bound on scattered partial-line HBM writes
//     (WRITE_SIZE == 600k x 64B exactly); occupancy is NOT the limiter.
// R13: prep fusion (swizzle+gate+convert) and dual-half agg KEPT (+15us);
//     bucket+gemm block-range fusion REGRESSED (gemm's 80VGPR/32KB LDS
//     footprint dropped bucket occupancy 48->26%) -> REVERTED.
// R14: scatter payload 8B->4B: edges store src only; agg computes
//     norm = dinv[src]*dinv[node] (dinv L2-hot, gather parallel to feature
//     gather). Pad = -1 (memset 0xFF), masked to nv=0 in agg. Also removes
//     bucket's dinv gathers and halves agg's edge-meta bytes.
// R15: R14 bench died on infra (UnresponsiveContainer) -- resubmitted as-is.
// ---------------------------------------------------------------------------

#define D 128   // feature dim (D_IN == HID == 128)

typedef __attribute__((ext_vector_type(8))) short short8;
typedef __attribute__((ext_vector_type(4))) float floatx4;

__device__ __forceinline__ unsigned bf16_rne(float x) {
    unsigned u = __float_as_uint(x);
    return (u + 0x7FFFu + ((u >> 16) & 1u)) >> 16;
}

__device__ __forceinline__ void gload_lds16(const void* g, void* l) {
    __builtin_amdgcn_global_load_lds(
        (const __attribute__((address_space(1))) unsigned int*)g,
        (__attribute__((address_space(3))) unsigned int*)l, 16, 0, 0);
}

__device__ __forceinline__ float h2f(unsigned short u) {
    return __half2float(__ushort_as_half(u));
}

// ---- prep: W swizzle (blocks 0..23) + gate MLP (24) + edge convert (25..) -
__global__ __launch_bounds__(256) void prep_kernel(
    const int* __restrict__ w, int* __restrict__ src32,
    int* __restrict__ dst32, int* __restrict__ counts, int E,
    const float* __restrict__ W0, const float* __restrict__ W1,
    const float* __restrict__ W2, short8* __restrict__ Wf_hi,
    short8* __restrict__ Wf_lo,
    const float* __restrict__ t, const float* __restrict__ Wg1,
    const float* __restrict__ bg1, const float* __restrict__ Wg2,
    const float* __restrict__ bg2, float* __restrict__ gate)
{
    int b = blockIdx.x;
    if (b < 24) {
        int f = b * 256 + threadIdx.x;   // 0..6143
        int layer = f >> 11;
        int fi = f & 2047;
        int lane = fi & 63;
        int tt = fi >> 6;                // kc*8 + n
        int kc = tt >> 3, n = tt & 7;
        const float* W = (layer == 0) ? W0 : (layer == 1) ? W1 : W2;
        int krow = kc * 32 + (lane >> 4) * 8;
        int col = n * 16 + (lane & 15);
        short8 hv, lv;
        #pragma unroll
        for (int j = 0; j < 8; j++) {
            float x = W[(size_t)(krow + j) * D + col];
            unsigned hb = bf16_rne(x);
            float hf = __uint_as_float(hb << 16);
            unsigned lb = bf16_rne(x - hf);
            hv[j] = (short)hb;
            lv[j] = (short)lb;
        }
        Wf_hi[f] = hv;
        Wf_lo[f] = lv;
        return;
    }
    if (b == 24) {
        __shared__ float u[D];
        int j = threadIdx.x;
        if (j < D) {
            float tv = t[0];
            u[j] = tanhf(tv * Wg1[j] + bg1[j]);
        }
        __syncthreads();
        if (j < D) {
            float s = bg2[j];
            #pragma unroll 8
            for (int k = 0; k < D; k++) s += u[k] * Wg2[k * D + j];
            gate[j] = 1.0f / (1.0f + expf(-s));
        }
        return;
    }
    // ---- edge convert (int64 auto-detect) + fused degree histogram ----
    __shared__ int flag;
    if (threadIdx.x == 0) {
        int z = 0;
        for (int k = 0; k < 64; k++) z |= w[2 * k + 1];
        flag = (z == 0) ? 1 : 0;   // all odd words zero => int64 layout
    }
    __syncthreads();
    int i64 = flag;
    int e = (b - 25) * 256 + threadIdx.x;
    if (e >= E) return;
    int s = i64 ? w[2 * e] : w[e];                       // little-endian low word
    int d = i64 ? w[2 * (E + e)] : w[E + e];
    src32[e] = s;
    dst32[e] = d;
    atomicAdd(&counts[d], 1);
}

// ------------------- multi-block exclusive scan ----------------------------
// Scans CAPACITY = (counts[i]+3)&~3  (external edges padded to x4; self-edge
// is handled inside agg, NOT stored in CSR).
#define SCHUNK 1024
__device__ __forceinline__ int cap4(int c) { return (c + 3) & ~3; }

__global__ __launch_bounds__(256) void scan_partial_kernel(
    const int* __restrict__ counts, int* __restrict__ bsums, int N)
{
    int base = blockIdx.x * SCHUNK + threadIdx.x * 4;
    int s = 0;
    if (base + 3 < N) {
        int4 v = *(const int4*)(counts + base);
        s = cap4(v.x) + cap4(v.y) + cap4(v.z) + cap4(v.w);
    } else {
        for (int k = 0; k < 4; k++) if (base + k < N) s += cap4(counts[base + k]);
    }
    #pragma unroll
    for (int off = 1; off < 64; off <<= 1) s += __shfl_xor(s, off);
    __shared__ int wsum[4];
    int lane = threadIdx.x & 63, wid = threadIdx.x >> 6;
    if (lane == 0) wsum[wid] = s;
    __syncthreads();
    if (threadIdx.x == 0)
        bsums[blockIdx.x] = wsum[0] + wsum[1] + wsum[2] + wsum[3];
}

__global__ __launch_bounds__(1024) void scan_bsums_kernel(
    int* __restrict__ bsums, int* __restrict__ total_out, int B)
{
    int t = threadIdx.x;
    int v = (t < B) ? bsums[t] : 0;
    int lane = t & 63, wid = t >> 6;
    int s = v;
    #pragma unroll
    for (int off = 1; off < 64; off <<= 1) {
        int n = __shfl_up(s, off);
        if (lane >= off) s += n;
    }
    __shared__ int wsum[16], wpre[16];
    if (lane == 63) wsum[wid] = s;
    __syncthreads();
    if (t < 16) {
        int ws = wsum[t];
        #pragma unroll
        for (int off = 1; off < 16; off <<= 1) {
            int n = __shfl_up(ws, off);
            if (t >= off) ws += n;
        }
        wpre[t] = ws;
    }
    __syncthreads();
    int wex = wid ? wpre[wid - 1] : 0;
    if (t < B) bsums[t] = wex + (s - v);      // exclusive
    if (t == 0) *total_out = wpre[15];        // grand total -> offsets[N]
}

__global__ __launch_bounds__(256) void scan_final_kernel(
    const int* __restrict__ counts, const int* __restrict__ bsums,
    int* __restrict__ offsets, int* __restrict__ cursor,
    float* __restrict__ dinv, int N)
{
    int base = blockIdx.x * SCHUNK + threadIdx.x * 4;
    int c[4];
    float dd[4];
    bool full = (base + 3 < N);
    if (full) {
        int4 v = *(const int4*)(counts + base);
        c[0] = cap4(v.x); c[1] = cap4(v.y); c[2] = cap4(v.z); c[3] = cap4(v.w);
        dd[0] = rsqrtf((float)(v.x + 1)); dd[1] = rsqrtf((float)(v.y + 1));
        dd[2] = rsqrtf((float)(v.z + 1)); dd[3] = rsqrtf((float)(v.w + 1));
    } else {
        for (int k = 0; k < 4; k++) {
            int r = (base + k < N) ? counts[base + k] : 0;
            c[k] = (base + k < N) ? cap4(r) : 0;
            dd[k] = rsqrtf((float)(r + 1));
        }
    }
    int sum = c[0] + c[1] + c[2] + c[3];
    int lane = threadIdx.x & 63, wid = threadIdx.x >> 6;
    int s = sum;
    #pragma unroll
    for (int off = 1; off < 64; off <<= 1) {
        int n = __shfl_up(s, off);
        if (lane >= off) s += n;
    }
    __shared__ int wsum[4], wpre[4];
    if (lane == 63) wsum[wid] = s;
    __syncthreads();
    if (threadIdx.x == 0) {
        int a = 0;
        #pragma unroll
        for (int k = 0; k < 4; k++) { wpre[k] = a; a += wsum[k]; }
    }
    __syncthreads();
    int e0 = bsums[blockIdx.x] + wpre[wid] + (s - sum);
    int4 o = make_int4(e0, e0 + c[0], e0 + c[0] + c[1], e0 + c[0] + c[1] + c[2]);
    float4 dv = make_float4(dd[0], dd[1], dd[2], dd[3]);
    if (full) {
        *(int4*)(offsets + base) = o;
        *(int4*)(cursor + base) = o;
        *(float4*)(dinv + base) = dv;
    } else {
        int oo[4] = { o.x, o.y, o.z, o.w };
        for (int k = 0; k < 4; k++)
            if (base + k < N) {
                offsets[base + k] = oo[k];
                cursor[base + k] = oo[k];
                dinv[base + k] = dd[k];
            }
    }
}

// ---------- bucket edges by dst (CSR, 4B src-only payload) -----------------
// One edge per thread: 2 coalesced loads -> atomic -> 4B scatter store.
// norm is computed later in agg from dinv (removes 2 gathers here, halves
// the scatter bytes). Pad slots stay -1 from the 0xFF memset.
__global__ __launch_bounds__(256) void bucket_kernel(
    const int* __restrict__ src32, const int* __restrict__ dst32,
    int* __restrict__ cursor, int* __restrict__ edges4, int E)
{
    int e = blockIdx.x * blockDim.x + threadIdx.x;
    if (e >= E) return;
    int s = src32[e];
    int d = dst32[e];
    int pos = atomicAdd(&cursor[d], 1);
    edges4[pos] = s;
}

// ----- cooperative Wf stage: 16KB (hi 8KB + lo 8KB) per kc into LDS --------
// Wfs layout (shorts): buf(kc&1)*8192 + [hi: chunk c*8 | lo: 4096 + c*8],
// chunk c = n*64 + lane  (16B per chunk, linear in lane => gload_lds-legal).
#define WSTAGE(kc_)                                                           \
    {                                                                         \
        short* wb_ = Wfs + (((kc_) & 1) ? 8192 : 0);                          \
        const short8* gh_ = Wf_hi + (size_t)(kc_) * 512;                      \
        const short8* gl_ = Wf_lo + (size_t)(kc_) * 512;                      \
        _Pragma("unroll")                                                     \
        for (int i_ = 0; i_ < 2; i_++) {                                      \
            int c_ = i_ * 256 + w * 64;                                       \
            gload_lds16(gh_ + c_ + lane, wb_ + c_ * 8);                       \
            gload_lds16(gl_ + c_ + lane, wb_ + 4096 + c_ * 8);                \
        }                                                                     \
    }

// ------------- shared MFMA inner block (A frags in registers) --------------
#define MFMA_BLOCK(kc)                                                        \
    {                                                                         \
        const short* wb = Wfs + (((kc) & 1) ? 8192 : 0);                      \
        _Pragma("unroll")                                                     \
        for (int n = 0; n < 8; n++) {                                         \
            short8 bh = *(const short8*)(wb + (n * 64 + lane) * 8);           \
            short8 bl = *(const short8*)(wb + 4096 + (n * 64 + lane) * 8);    \
            acc[0][n] = __builtin_amdgcn_mfma_f32_16x16x32_bf16(ah0, bh, acc[0][n], 0, 0, 0); \
            acc[0][n] = __builtin_amdgcn_mfma_f32_16x16x32_bf16(ah0, bl, acc[0][n], 0, 0, 0); \
            acc[0][n] = __builtin_amdgcn_mfma_f32_16x16x32_bf16(al0, bh, acc[0][n], 0, 0, 0); \
            acc[1][n] = __builtin_amdgcn_mfma_f32_16x16x32_bf16(ah1, bh, acc[1][n], 0, 0, 0); \
            acc[1][n] = __builtin_amdgcn_mfma_f32_16x16x32_bf16(ah1, bl, acc[1][n], 0, 0, 0); \
            acc[1][n] = __builtin_amdgcn_mfma_f32_16x16x32_bf16(al1, bh, acc[1][n], 0, 0, 0); \
        }                                                                     \
    }

#define EPILOGUE()                                                            \
    _Pragma("unroll")                                                         \
    for (int rt = 0; rt < 2; rt++) {                                          \
        _Pragma("unroll")                                                     \
        for (int reg = 0; reg < 4; reg++) {                                   \
            int row = rowbase + rt * 16 + qd * 4 + reg;                       \
            if (row < M) {                                                    \
                unsigned short* hp = H16 + (size_t)row * D + m16;             \
                _Pragma("unroll")                                             \
                for (int n = 0; n < 8; n++)                                   \
                    hp[n * 16] = __half_as_ushort(__float2half(acc[rt][n][reg])); \
            }                                                                 \
        }                                                                     \
    }

// ------------- GEMM variant A: fp32 X input (layer 0 only) -----------------
#define GBM 128
__device__ __forceinline__ void cvt8(const float* f, short8& hi, short8& lo) {
    #pragma unroll
    for (int j = 0; j < 8; j++) {
        unsigned hb = bf16_rne(f[j]);
        float hf = __uint_as_float(hb << 16);
        unsigned lb = bf16_rne(f[j] - hf);
        hi[j] = (short)hb;
        lo[j] = (short)lb;
    }
}

__global__ __launch_bounds__(256) void gemm_f32_kernel(
    const float* __restrict__ X, const short8* __restrict__ Wf_hi,
    const short8* __restrict__ Wf_lo, unsigned short* __restrict__ H16, int M)
{
    __shared__ short Wfs[16384];   // 32KB: 2 bufs x (hi 8KB + lo 8KB)
    int tid = threadIdx.x;
    int w = tid >> 6, lane = tid & 63;
    int m16 = lane & 15, qd = lane >> 4;
    int rowbase = blockIdx.x * GBM + w * 32;

    int r0 = rowbase + m16;      if (r0 >= M) r0 = M - 1;
    int r1 = rowbase + m16 + 16; if (r1 >= M) r1 = M - 1;
    const float* xp0 = X + (size_t)r0 * D + qd * 8;
    const float* xp1 = X + (size_t)r1 * D + qd * 8;

    floatx4 acc[2][8];
    #pragma unroll
    for (int rt = 0; rt < 2; rt++)
        #pragma unroll
        for (int n = 0; n < 8; n++)
            acc[rt][n] = (floatx4)(0.f);

    #define LOADA(kc_, A0, A1)                                              \
        {                                                                   \
            *(float4*)(A0)     = *(const float4*)(xp0 + (kc_) * 32);        \
            *(float4*)(A0 + 4) = *(const float4*)(xp0 + (kc_) * 32 + 4);    \
            *(float4*)(A1)     = *(const float4*)(xp1 + (kc_) * 32);        \
            *(float4*)(A1 + 4) = *(const float4*)(xp1 + (kc_) * 32 + 4);    \
        }

    float a0c[8], a1c[8], a0n[8], a1n[8];
    WSTAGE(0)
    LOADA(0, a0c, a1c)

    #pragma unroll
    for (int kc = 0; kc < 4; kc++) {
        __syncthreads();     // drains vmcnt: Wf(kc) in LDS, A(kc) in regs
        if (kc < 3) {
            WSTAGE(kc + 1)
            LOADA(kc + 1, a0n, a1n)
        }
        short8 ah0, al0, ah1, al1;
        cvt8(a0c, ah0, al0);
        cvt8(a1c, ah1, al1);
        MFMA_BLOCK(kc)
        if (kc < 3) {
            #pragma unroll
            for (int z = 0; z < 8; z++) { a0c[z] = a0n[z]; a1c[z] = a1n[z]; }
        }
    }
    #undef LOADA
    EPILOGUE()
}

// ------ GEMM variant B: pre-split bf16 hi/lo planes input (layers 1,2) -----
__global__ __launch_bounds__(256) void gemm_bf16_kernel(
    const unsigned short* __restrict__ Xh, const unsigned short* __restrict__ Xl,
    const short8* __restrict__ Wf_hi, const short8* __restrict__ Wf_lo,
    unsigned short* __restrict__ H16, int M)
{
    __shared__ short Wfs[16384];   // 32KB: 2 bufs x (hi 8KB + lo 8KB)
    int tid = threadIdx.x;
    int w = tid >> 6, lane = tid & 63;
    int m16 = lane & 15, qd = lane >> 4;
    int rowbase = blockIdx.x * GBM + w * 32;

    int r0 = rowbase + m16;      if (r0 >= M) r0 = M - 1;
    int r1 = rowbase + m16 + 16; if (r1 >= M) r1 = M - 1;
    const unsigned short* xh0 = Xh + (size_t)r0 * D + qd * 8;
    const unsigned short* xh1 = Xh + (size_t)r1 * D + qd * 8;
    const unsigned short* xl0 = Xl + (size_t)r0 * D + qd * 8;
    const unsigned short* xl1 = Xl + (size_t)r1 * D + qd * 8;

    floatx4 acc[2][8];
    #pragma unroll
    for (int rt = 0; rt < 2; rt++)
        #pragma unroll
        for (int n = 0; n < 8; n++)
            acc[rt][n] = (floatx4)(0.f);

    #define LOADB(kc_, H0, L0, H1, L1)                                      \
        {                                                                   \
            H0 = *(const short8*)(xh0 + (kc_) * 32);                        \
            H1 = *(const short8*)(xh1 + (kc_) * 32);                        \
            L0 = *(const short8*)(xl0 + (kc_) * 32);                        \
            L1 = *(const short8*)(xl1 + (kc_) * 32);                        \
        }

    short8 ah0, al0, ah1, al1, nh0, nl0, nh1, nl1;
    WSTAGE(0)
    LOADB(0, ah0, al0, ah1, al1)

    #pragma unroll
    for (int kc = 0; kc < 4; kc++) {
        __syncthreads();     // drains vmcnt: Wf(kc) in LDS, A(kc) in regs
        if (kc < 3) {
            WSTAGE(kc + 1)
            LOADB(kc + 1, nh0, nl0, nh1, nl1)
        }
        MFMA_BLOCK(kc)
        if (kc < 3) { ah0 = nh0; al0 = nl0; ah1 = nh1; al1 = nl1; }
    }
    #undef LOADB
    EPILOGUE()
}

// ------- per-node aggregation: FULL wave per node, dual-quad halves --------
// Edges are 4B src-only; pad = -1 -> nv forced to 0 (no NaN path: mask is
// applied to nv before the FMA). norm = dinv[src]*dinv[node], dinv gather
// issues in parallel with the feature gather. Two half-waves process
// alternating quads; merge via __shfl_xor(32).
__global__ __launch_bounds__(256) void agg_kernel(
    const unsigned short* __restrict__ H16, const int* __restrict__ edges4,
    const int* __restrict__ offsets, const float* __restrict__ dinv,
    const float* __restrict__ bias, const float* __restrict__ gate,
    float* __restrict__ outF, unsigned short* __restrict__ outH,
    unsigned short* __restrict__ outL, int M, int writeF32)
{
    int t = threadIdx.x;
    int wv = t >> 6;                  // wave 0..3
    int half = (t >> 5) & 1;          // half-wave within the wave
    int l32 = t & 31;
    int node = blockIdx.x * 4 + wv;
    if (node >= M) return;

    int beg = offsets[node];
    int end = offsets[node + 1];
    float dv = dinv[node];
    const unsigned short* __restrict__ Hc = H16 + l32 * 4;
    // self row: issue load early, consume after the gather loop
    ushort4 us = *(const ushort4*)(Hc + (size_t)node * D);
    float4 acc = make_float4(0.f, 0.f, 0.f, 0.f);

    int j0 = beg + 4 * half;
    int4 m = make_int4(-1, -1, -1, -1);
    if (j0 < end) m = *(const int4*)(edges4 + j0);   // 4 srcs
    for (int j = j0; j < end; j += 8) {
        int jn = j + 8;
        int jp = (jn < end) ? jn : j0;               // clamped: always valid
        int4 q = *(const int4*)(edges4 + jp);
        int c0 = m.x < 0 ? 0 : m.x;
        int c1 = m.y < 0 ? 0 : m.y;
        int c2 = m.z < 0 ? 0 : m.z;
        int c3 = m.w < 0 ? 0 : m.w;
        float d0 = dinv[c0], d1 = dinv[c1], d2 = dinv[c2], d3 = dinv[c3];
        ushort4 u0 = *(const ushort4*)(Hc + (size_t)c0 * D);
        ushort4 u1 = *(const ushort4*)(Hc + (size_t)c1 * D);
        ushort4 u2 = *(const ushort4*)(Hc + (size_t)c2 * D);
        ushort4 u3 = *(const ushort4*)(Hc + (size_t)c3 * D);
        float n0 = (m.x < 0) ? 0.f : d0 * dv;
        float n1 = (m.y < 0) ? 0.f : d1 * dv;
        float n2 = (m.z < 0) ? 0.f : d2 * dv;
        float n3 = (m.w < 0) ? 0.f : d3 * dv;
        acc.x = fmaf(h2f(u3.x), n3, fmaf(h2f(u2.x), n2, fmaf(h2f(u1.x), n1, fmaf(h2f(u0.x), n0, acc.x))));
        acc.y = fmaf(h2f(u3.y), n3, fmaf(h2f(u2.y), n2, fmaf(h2f(u1.y), n1, fmaf(h2f(u0.y), n0, acc.y))));
        acc.z = fmaf(h2f(u3.z), n3, fmaf(h2f(u2.z), n2, fmaf(h2f(u1.z), n1, fmaf(h2f(u0.z), n0, acc.z))));
        acc.w = fmaf(h2f(u3.w), n3, fmaf(h2f(u2.w), n2, fmaf(h2f(u1.w), n1, fmaf(h2f(u0.w), n0, acc.w))));
        m = q;
    }

    // merge the two halves (lane l <-> l+32 hold the same feature slot)
    acc.x += __shfl_xor(acc.x, 32);
    acc.y += __shfl_xor(acc.y, 32);
    acc.z += __shfl_xor(acc.z, 32);
    acc.w += __shfl_xor(acc.w, 32);

    if (half == 0) {
        // self-loop term: norm = dinv^2 = 1/deg (exact, matches reference)
        float nself = dv * dv;
        acc.x = fmaf(h2f(us.x), nself, acc.x);
        acc.y = fmaf(h2f(us.y), nself, acc.y);
        acc.z = fmaf(h2f(us.z), nself, acc.z);
        acc.w = fmaf(h2f(us.w), nself, acc.w);

        float4 bv = *(const float4*)(bias + l32 * 4);
        float4 gv = *(const float4*)(gate + l32 * 4);
        acc.x = fmaxf(acc.x + bv.x, 0.f) * gv.x;
        acc.y = fmaxf(acc.y + bv.y, 0.f) * gv.y;
        acc.z = fmaxf(acc.z + bv.z, 0.f) * gv.z;
        acc.w = fmaxf(acc.w + bv.w, 0.f) * gv.w;

        if (writeF32) {
            *(float4*)(outF + (size_t)node * D + l32 * 4) = acc;
        } else {
            unsigned hx = bf16_rne(acc.x), hy = bf16_rne(acc.y);
            unsigned hz = bf16_rne(acc.z), hw4 = bf16_rne(acc.w);
            ushort4 hs = make_ushort4((unsigned short)hx, (unsigned short)hy,
                                      (unsigned short)hz, (unsigned short)hw4);
            ushort4 ls = make_ushort4(
                (unsigned short)bf16_rne(acc.x - __uint_as_float(hx << 16)),
                (unsigned short)bf16_rne(acc.y - __uint_as_float(hy << 16)),
                (unsigned short)bf16_rne(acc.z - __uint_as_float(hz << 16)),
                (unsigned short)bf16_rne(acc.w - __uint_as_float(hw4 << 16)));
            *(ushort4*)(outH + (size_t)node * D + l32 * 4) = hs;
            *(ushort4*)(outL + (size_t)node * D + l32 * 4) = ls;
        }
    }
}

// ---------------------------------------------------------------------------
static inline size_t align_up(size_t v, size_t a) { return (v + a - 1) & ~(a - 1); }

extern "C" void kernel_launch(void* const* d_in, const int* in_sizes, int n_in,
                              void* d_out, int out_size, void* d_ws, size_t ws_size,
                              hipStream_t stream)
{
    const float* x   = (const float*)d_in[0];
    const int*   ei  = (const int*)d_in[1];   // int32 or int64 (auto-detected)
    const float* ts  = (const float*)d_in[2];
    const float* Wl[3] = { (const float*)d_in[3], (const float*)d_in[5], (const float*)d_in[7] };
    const float* bl[3] = { (const float*)d_in[4], (const float*)d_in[6], (const float*)d_in[8] };
    const float* Wg1 = (const float*)d_in[9];
    const float* bg1 = (const float*)d_in[10];
    const float* Wg2 = (const float*)d_in[11];
    const float* bg2 = (const float*)d_in[12];

    const int N = in_sizes[0] / D;      // 100000
    const int E = in_sizes[1] / 2;      // 600000
    const int NB = (N + SCHUNK - 1) / SCHUNK;   // scan blocks
    const size_t ECAP = (size_t)E + 3 * (size_t)N;  // padded CSR worst case

    // workspace carve (all 256B aligned)
    char* p = (char*)d_ws;
    unsigned short* h16 = (unsigned short*)p; p += align_up((size_t)N * D * 2, 256);
    unsigned short* xh  = (unsigned short*)p; p += align_up((size_t)N * D * 2, 256);
    unsigned short* xl  = (unsigned short*)p; p += align_up((size_t)N * D * 2, 256);
    int* src32  = (int*)p;   p += align_up((size_t)E * 4, 256);
    int* dst32  = (int*)p;   p += align_up((size_t)E * 4, 256);
    int* counts = (int*)p;   p += align_up((size_t)N * 4, 256);
    float* dinv = (float*)p; p += align_up((size_t)N * 4, 256);
    int* offs   = (int*)p;   p += align_up((size_t)(N + 1) * 4, 256);
    int* cursor = (int*)p;   p += align_up((size_t)N * 4, 256);
    int* edges4 = (int*)p;   p += align_up(ECAP * 4, 256);
    float* gate = (float*)p; p += align_up((size_t)D * 4, 256);
    int* bsums  = (int*)p;   p += align_up((size_t)NB * 4, 256);
    short8* Wf_hi = (short8*)p; p += align_up((size_t)3 * 2048 * 16, 256);
    short8* Wf_lo = (short8*)p; p += align_up((size_t)3 * 2048 * 16, 256);
    (void)ws_size; (void)n_in; (void)out_size;

    (void)hipMemsetAsync(counts, 0, (size_t)N * 4, stream);
    (void)hipMemsetAsync(edges4, 0xFF, ECAP * 4, stream);  // pad entries = -1

    int egrid = (E + 255) / 256;
    prep_kernel<<<25 + egrid, 256, 0, stream>>>(
        ei, src32, dst32, counts, E,
        Wl[0], Wl[1], Wl[2], Wf_hi, Wf_lo,
        ts, Wg1, bg1, Wg2, bg2, gate);
    scan_partial_kernel<<<NB, 256, 0, stream>>>(counts, bsums, N);
    scan_bsums_kernel<<<1, 1024, 0, stream>>>(bsums, offs + N, NB);
    scan_final_kernel<<<NB, 256, 0, stream>>>(counts, bsums, offs, cursor, dinv, N);
    bucket_kernel<<<egrid, 256, 0, stream>>>(src32, dst32, cursor, edges4, E);

    int ggrid = (N + GBM - 1) / GBM;
    int agrid = (N + 3) / 4;
    // layer 0: fp32 input
    gemm_f32_kernel<<<ggrid, 256, 0, stream>>>(x, Wf_hi, Wf_lo, h16, N);
    agg_kernel<<<agrid, 256, 0, stream>>>(h16, edges4, offs, dinv, bl[0], gate,
                                          nullptr, xh, xl, N, 0);
    // layer 1: bf16-plane input
    gemm_bf16_kernel<<<ggrid, 256, 0, stream>>>(xh, xl, Wf_hi + 2048, Wf_lo + 2048, h16, N);
    agg_kernel<<<agrid, 256, 0, stream>>>(h16, edges4, offs, dinv, bl[1], gate,
                                          nullptr, xh, xl, N, 0);
    // layer 2: bf16-plane input, fp32 output
    gemm_bf16_kernel<<<ggrid, 256, 0, stream>>>(xh, xl, Wf_hi + 4096, Wf_lo + 4096, h16, N);
    agg_kernel<<<agrid, 256, 0, stream>>>(h16, edges4, offs, dinv, bl[2], gate,
                                          (float*)d_out, nullptr, nullptr, N, 1);
}

// Round 7
// 259.728 us; speedup vs baseline: 1.0399x; 1.0399x over previous
//
#include <hip/hip_runtime.h>
#include <hip/hip_bf16.h>
#include <hip/hip_fp16.h>
#include <math.h>

// ---------------------------------------------------------------------------
// DynamicGCN: 3x (GCNConv -> ReLU -> *gate)
// R1: multi-block scan, hist fused into convert, dinv folded into scan C.
// R2: split-bf16 MFMA GEMM, W pre-swizzled into B-fragment order.
// R9: layer outputs stored as PRE-SPLIT bf16 hi/lo planes for layers 1/2.
// R10: agg CSR padded to x4 (tail-free loop); self-edge folded into agg.
// R11: Wf staged per-kc into LDS (double-buffered); X loads global->reg;
//     agg half-wave/node, 4-deep, edge-meta software-pipelined (~38us).
// R12: bucket is throughput-bound on scattered partial-line HBM writes;
//     occupancy is NOT the limiter (one-edge-per-thread: occ 31->48%, flat).
// R13: prep fusion (swizzle+gate+convert) KEPT; bucket+gemm fusion REVERTED.
// R14: 4B scatter payload GOOD for bucket (-15us) but recomputing
//     norm IN agg's inner loop REGRESSED agg 39->46 (VALUBusy 33->55%:
//     dinv gather + mask on the per-edge critical path).
// R16: keep 4B bucket scatter; add expand_kernel (coalesced linear pass)
//     converting edges4 -> edges8=(src, dinv[src]); pads become (0, 0.0f)
//     so agg is mask-free; agg reverts to R11 shape with nv = npartial*dv.
// ---------------------------------------------------------------------------

#define D 128   // feature dim (D_IN == HID == 128)

typedef __attribute__((ext_vector_type(8))) short short8;
typedef __attribute__((ext_vector_type(4))) float floatx4;

__device__ __forceinline__ unsigned bf16_rne(float x) {
    unsigned u = __float_as_uint(x);
    return (u + 0x7FFFu + ((u >> 16) & 1u)) >> 16;
}

__device__ __forceinline__ void gload_lds16(const void* g, void* l) {
    __builtin_amdgcn_global_load_lds(
        (const __attribute__((address_space(1))) unsigned int*)g,
        (__attribute__((address_space(3))) unsigned int*)l, 16, 0, 0);
}

__device__ __forceinline__ float h2f(unsigned short u) {
    return __half2float(__ushort_as_half(u));
}

// ---- prep: W swizzle (blocks 0..23) + gate MLP (24) + edge convert (25..) -
__global__ __launch_bounds__(256) void prep_kernel(
    const int* __restrict__ w, int* __restrict__ src32,
    int* __restrict__ dst32, int* __restrict__ counts, int E,
    const float* __restrict__ W0, const float* __restrict__ W1,
    const float* __restrict__ W2, short8* __restrict__ Wf_hi,
    short8* __restrict__ Wf_lo,
    const float* __restrict__ t, const float* __restrict__ Wg1,
    const float* __restrict__ bg1, const float* __restrict__ Wg2,
    const float* __restrict__ bg2, float* __restrict__ gate)
{
    int b = blockIdx.x;
    if (b < 24) {
        int f = b * 256 + threadIdx.x;   // 0..6143
        int layer = f >> 11;
        int fi = f & 2047;
        int lane = fi & 63;
        int tt = fi >> 6;                // kc*8 + n
        int kc = tt >> 3, n = tt & 7;
        const float* W = (layer == 0) ? W0 : (layer == 1) ? W1 : W2;
        int krow = kc * 32 + (lane >> 4) * 8;
        int col = n * 16 + (lane & 15);
        short8 hv, lv;
        #pragma unroll
        for (int j = 0; j < 8; j++) {
            float x = W[(size_t)(krow + j) * D + col];
            unsigned hb = bf16_rne(x);
            float hf = __uint_as_float(hb << 16);
            unsigned lb = bf16_rne(x - hf);
            hv[j] = (short)hb;
            lv[j] = (short)lb;
        }
        Wf_hi[f] = hv;
        Wf_lo[f] = lv;
        return;
    }
    if (b == 24) {
        __shared__ float u[D];
        int j = threadIdx.x;
        if (j < D) {
            float tv = t[0];
            u[j] = tanhf(tv * Wg1[j] + bg1[j]);
        }
        __syncthreads();
        if (j < D) {
            float s = bg2[j];
            #pragma unroll 8
            for (int k = 0; k < D; k++) s += u[k] * Wg2[k * D + j];
            gate[j] = 1.0f / (1.0f + expf(-s));
        }
        return;
    }
    // ---- edge convert (int64 auto-detect) + fused degree histogram ----
    __shared__ int flag;
    if (threadIdx.x == 0) {
        int z = 0;
        for (int k = 0; k < 64; k++) z |= w[2 * k + 1];
        flag = (z == 0) ? 1 : 0;   // all odd words zero => int64 layout
    }
    __syncthreads();
    int i64 = flag;
    int e = (b - 25) * 256 + threadIdx.x;
    if (e >= E) return;
    int s = i64 ? w[2 * e] : w[e];                       // little-endian low word
    int d = i64 ? w[2 * (E + e)] : w[E + e];
    src32[e] = s;
    dst32[e] = d;
    atomicAdd(&counts[d], 1);
}

// ------------------- multi-block exclusive scan ----------------------------
// Scans CAPACITY = (counts[i]+3)&~3  (external edges padded to x4; self-edge
// is handled inside agg, NOT stored in CSR).
#define SCHUNK 1024
__device__ __forceinline__ int cap4(int c) { return (c + 3) & ~3; }

__global__ __launch_bounds__(256) void scan_partial_kernel(
    const int* __restrict__ counts, int* __restrict__ bsums, int N)
{
    int base = blockIdx.x * SCHUNK + threadIdx.x * 4;
    int s = 0;
    if (base + 3 < N) {
        int4 v = *(const int4*)(counts + base);
        s = cap4(v.x) + cap4(v.y) + cap4(v.z) + cap4(v.w);
    } else {
        for (int k = 0; k < 4; k++) if (base + k < N) s += cap4(counts[base + k]);
    }
    #pragma unroll
    for (int off = 1; off < 64; off <<= 1) s += __shfl_xor(s, off);
    __shared__ int wsum[4];
    int lane = threadIdx.x & 63, wid = threadIdx.x >> 6;
    if (lane == 0) wsum[wid] = s;
    __syncthreads();
    if (threadIdx.x == 0)
        bsums[blockIdx.x] = wsum[0] + wsum[1] + wsum[2] + wsum[3];
}

__global__ __launch_bounds__(1024) void scan_bsums_kernel(
    int* __restrict__ bsums, int* __restrict__ total_out, int B)
{
    int t = threadIdx.x;
    int v = (t < B) ? bsums[t] : 0;
    int lane = t & 63, wid = t >> 6;
    int s = v;
    #pragma unroll
    for (int off = 1; off < 64; off <<= 1) {
        int n = __shfl_up(s, off);
        if (lane >= off) s += n;
    }
    __shared__ int wsum[16], wpre[16];
    if (lane == 63) wsum[wid] = s;
    __syncthreads();
    if (t < 16) {
        int ws = wsum[t];
        #pragma unroll
        for (int off = 1; off < 16; off <<= 1) {
            int n = __shfl_up(ws, off);
            if (t >= off) ws += n;
        }
        wpre[t] = ws;
    }
    __syncthreads();
    int wex = wid ? wpre[wid - 1] : 0;
    if (t < B) bsums[t] = wex + (s - v);      // exclusive
    if (t == 0) *total_out = wpre[15];        // grand total -> offsets[N]
}

__global__ __launch_bounds__(256) void scan_final_kernel(
    const int* __restrict__ counts, const int* __restrict__ bsums,
    int* __restrict__ offsets, int* __restrict__ cursor,
    float* __restrict__ dinv, int N)
{
    int base = blockIdx.x * SCHUNK + threadIdx.x * 4;
    int c[4];
    float dd[4];
    bool full = (base + 3 < N);
    if (full) {
        int4 v = *(const int4*)(counts + base);
        c[0] = cap4(v.x); c[1] = cap4(v.y); c[2] = cap4(v.z); c[3] = cap4(v.w);
        dd[0] = rsqrtf((float)(v.x + 1)); dd[1] = rsqrtf((float)(v.y + 1));
        dd[2] = rsqrtf((float)(v.z + 1)); dd[3] = rsqrtf((float)(v.w + 1));
    } else {
        for (int k = 0; k < 4; k++) {
            int r = (base + k < N) ? counts[base + k] : 0;
            c[k] = (base + k < N) ? cap4(r) : 0;
            dd[k] = rsqrtf((float)(r + 1));
        }
    }
    int sum = c[0] + c[1] + c[2] + c[3];
    int lane = threadIdx.x & 63, wid = threadIdx.x >> 6;
    int s = sum;
    #pragma unroll
    for (int off = 1; off < 64; off <<= 1) {
        int n = __shfl_up(s, off);
        if (lane >= off) s += n;
    }
    __shared__ int wsum[4], wpre[4];
    if (lane == 63) wsum[wid] = s;
    __syncthreads();
    if (threadIdx.x == 0) {
        int a = 0;
        #pragma unroll
        for (int k = 0; k < 4; k++) { wpre[k] = a; a += wsum[k]; }
    }
    __syncthreads();
    int e0 = bsums[blockIdx.x] + wpre[wid] + (s - sum);
    int4 o = make_int4(e0, e0 + c[0], e0 + c[0] + c[1], e0 + c[0] + c[1] + c[2]);
    float4 dv = make_float4(dd[0], dd[1], dd[2], dd[3]);
    if (full) {
        *(int4*)(offsets + base) = o;
        *(int4*)(cursor + base) = o;
        *(float4*)(dinv + base) = dv;
    } else {
        int oo[4] = { o.x, o.y, o.z, o.w };
        for (int k = 0; k < 4; k++)
            if (base + k < N) {
                offsets[base + k] = oo[k];
                cursor[base + k] = oo[k];
                dinv[base + k] = dd[k];
            }
    }
}

// ---------- bucket edges by dst (CSR, 4B src-only payload) -----------------
// One edge per thread: 2 coalesced loads -> atomic -> 4B scatter store.
__global__ __launch_bounds__(256) void bucket_kernel(
    const int* __restrict__ src32, const int* __restrict__ dst32,
    int* __restrict__ cursor, int* __restrict__ edges4, int E)
{
    int e = blockIdx.x * blockDim.x + threadIdx.x;
    if (e >= E) return;
    int s = src32[e];
    int d = dst32[e];
    int pos = atomicAdd(&cursor[d], 1);
    edges4[pos] = s;
}

// ---------- expand: edges4 -> edges8 = (src, dinv[src]); pads -> (0,0) -----
// Fully coalesced linear pass; dinv is 400KB (L2-hot). Moves the norm
// recompute OFF agg's per-edge critical path (R14's mistake).
__global__ __launch_bounds__(256) void expand_kernel(
    const int* __restrict__ edges4, const float* __restrict__ dinv,
    int2* __restrict__ edges8, int cap)
{
    int i = blockIdx.x * blockDim.x + threadIdx.x;
    if (i >= cap) return;
    int s = edges4[i];
    int ss = (s < 0) ? 0 : s;
    float f = (s < 0) ? 0.f : dinv[ss];
    edges8[i] = make_int2(ss, __float_as_int(f));
}

// ----- cooperative Wf stage: 16KB (hi 8KB + lo 8KB) per kc into LDS --------
// Wfs layout (shorts): buf(kc&1)*8192 + [hi: chunk c*8 | lo: 4096 + c*8],
// chunk c = n*64 + lane  (16B per chunk, linear in lane => gload_lds-legal).
#define WSTAGE(kc_)                                                           \
    {                                                                         \
        short* wb_ = Wfs + (((kc_) & 1) ? 8192 : 0);                          \
        const short8* gh_ = Wf_hi + (size_t)(kc_) * 512;                      \
        const short8* gl_ = Wf_lo + (size_t)(kc_) * 512;                      \
        _Pragma("unroll")                                                     \
        for (int i_ = 0; i_ < 2; i_++) {                                      \
            int c_ = i_ * 256 + w * 64;                                       \
            gload_lds16(gh_ + c_ + lane, wb_ + c_ * 8);                       \
            gload_lds16(gl_ + c_ + lane, wb_ + 4096 + c_ * 8);                \
        }                                                                     \
    }

// ------------- shared MFMA inner block (A frags in registers) --------------
#define MFMA_BLOCK(kc)                                                        \
    {                                                                         \
        const short* wb = Wfs + (((kc) & 1) ? 8192 : 0);                      \
        _Pragma("unroll")                                                     \
        for (int n = 0; n < 8; n++) {                                         \
            short8 bh = *(const short8*)(wb + (n * 64 + lane) * 8);           \
            short8 bl = *(const short8*)(wb + 4096 + (n * 64 + lane) * 8);    \
            acc[0][n] = __builtin_amdgcn_mfma_f32_16x16x32_bf16(ah0, bh, acc[0][n], 0, 0, 0); \
            acc[0][n] = __builtin_amdgcn_mfma_f32_16x16x32_bf16(ah0, bl, acc[0][n], 0, 0, 0); \
            acc[0][n] = __builtin_amdgcn_mfma_f32_16x16x32_bf16(al0, bh, acc[0][n], 0, 0, 0); \
            acc[1][n] = __builtin_amdgcn_mfma_f32_16x16x32_bf16(ah1, bh, acc[1][n], 0, 0, 0); \
            acc[1][n] = __builtin_amdgcn_mfma_f32_16x16x32_bf16(ah1, bl, acc[1][n], 0, 0, 0); \
            acc[1][n] = __builtin_amdgcn_mfma_f32_16x16x32_bf16(al1, bh, acc[1][n], 0, 0, 0); \
        }                                                                     \
    }

#define EPILOGUE()                                                            \
    _Pragma("unroll")                                                         \
    for (int rt = 0; rt < 2; rt++) {                                          \
        _Pragma("unroll")                                                     \
        for (int reg = 0; reg < 4; reg++) {                                   \
            int row = rowbase + rt * 16 + qd * 4 + reg;                       \
            if (row < M) {                                                    \
                unsigned short* hp = H16 + (size_t)row * D + m16;             \
                _Pragma("unroll")                                             \
                for (int n = 0; n < 8; n++)                                   \
                    hp[n * 16] = __half_as_ushort(__float2half(acc[rt][n][reg])); \
            }                                                                 \
        }                                                                     \
    }

// ------------- GEMM variant A: fp32 X input (layer 0 only) -----------------
#define GBM 128
__device__ __forceinline__ void cvt8(const float* f, short8& hi, short8& lo) {
    #pragma unroll
    for (int j = 0; j < 8; j++) {
        unsigned hb = bf16_rne(f[j]);
        float hf = __uint_as_float(hb << 16);
        unsigned lb = bf16_rne(f[j] - hf);
        hi[j] = (short)hb;
        lo[j] = (short)lb;
    }
}

__global__ __launch_bounds__(256) void gemm_f32_kernel(
    const float* __restrict__ X, const short8* __restrict__ Wf_hi,
    const short8* __restrict__ Wf_lo, unsigned short* __restrict__ H16, int M)
{
    __shared__ short Wfs[16384];   // 32KB: 2 bufs x (hi 8KB + lo 8KB)
    int tid = threadIdx.x;
    int w = tid >> 6, lane = tid & 63;
    int m16 = lane & 15, qd = lane >> 4;
    int rowbase = blockIdx.x * GBM + w * 32;

    int r0 = rowbase + m16;      if (r0 >= M) r0 = M - 1;
    int r1 = rowbase + m16 + 16; if (r1 >= M) r1 = M - 1;
    const float* xp0 = X + (size_t)r0 * D + qd * 8;
    const float* xp1 = X + (size_t)r1 * D + qd * 8;

    floatx4 acc[2][8];
    #pragma unroll
    for (int rt = 0; rt < 2; rt++)
        #pragma unroll
        for (int n = 0; n < 8; n++)
            acc[rt][n] = (floatx4)(0.f);

    #define LOADA(kc_, A0, A1)                                              \
        {                                                                   \
            *(float4*)(A0)     = *(const float4*)(xp0 + (kc_) * 32);        \
            *(float4*)(A0 + 4) = *(const float4*)(xp0 + (kc_) * 32 + 4);    \
            *(float4*)(A1)     = *(const float4*)(xp1 + (kc_) * 32);        \
            *(float4*)(A1 + 4) = *(const float4*)(xp1 + (kc_) * 32 + 4);    \
        }

    float a0c[8], a1c[8], a0n[8], a1n[8];
    WSTAGE(0)
    LOADA(0, a0c, a1c)

    #pragma unroll
    for (int kc = 0; kc < 4; kc++) {
        __syncthreads();     // drains vmcnt: Wf(kc) in LDS, A(kc) in regs
        if (kc < 3) {
            WSTAGE(kc + 1)
            LOADA(kc + 1, a0n, a1n)
        }
        short8 ah0, al0, ah1, al1;
        cvt8(a0c, ah0, al0);
        cvt8(a1c, ah1, al1);
        MFMA_BLOCK(kc)
        if (kc < 3) {
            #pragma unroll
            for (int z = 0; z < 8; z++) { a0c[z] = a0n[z]; a1c[z] = a1n[z]; }
        }
    }
    #undef LOADA
    EPILOGUE()
}

// ------ GEMM variant B: pre-split bf16 hi/lo planes input (layers 1,2) -----
__global__ __launch_bounds__(256) void gemm_bf16_kernel(
    const unsigned short* __restrict__ Xh, const unsigned short* __restrict__ Xl,
    const short8* __restrict__ Wf_hi, const short8* __restrict__ Wf_lo,
    unsigned short* __restrict__ H16, int M)
{
    __shared__ short Wfs[16384];   // 32KB: 2 bufs x (hi 8KB + lo 8KB)
    int tid = threadIdx.x;
    int w = tid >> 6, lane = tid & 63;
    int m16 = lane & 15, qd = lane >> 4;
    int rowbase = blockIdx.x * GBM + w * 32;

    int r0 = rowbase + m16;      if (r0 >= M) r0 = M - 1;
    int r1 = rowbase + m16 + 16; if (r1 >= M) r1 = M - 1;
    const unsigned short* xh0 = Xh + (size_t)r0 * D + qd * 8;
    const unsigned short* xh1 = Xh + (size_t)r1 * D + qd * 8;
    const unsigned short* xl0 = Xl + (size_t)r0 * D + qd * 8;
    const unsigned short* xl1 = Xl + (size_t)r1 * D + qd * 8;

    floatx4 acc[2][8];
    #pragma unroll
    for (int rt = 0; rt < 2; rt++)
        #pragma unroll
        for (int n = 0; n < 8; n++)
            acc[rt][n] = (floatx4)(0.f);

    #define LOADB(kc_, H0, L0, H1, L1)                                      \
        {                                                                   \
            H0 = *(const short8*)(xh0 + (kc_) * 32);                        \
            H1 = *(const short8*)(xh1 + (kc_) * 32);                        \
            L0 = *(const short8*)(xl0 + (kc_) * 32);                        \
            L1 = *(const short8*)(xl1 + (kc_) * 32);                        \
        }

    short8 ah0, al0, ah1, al1, nh0, nl0, nh1, nl1;
    WSTAGE(0)
    LOADB(0, ah0, al0, ah1, al1)

    #pragma unroll
    for (int kc = 0; kc < 4; kc++) {
        __syncthreads();     // drains vmcnt: Wf(kc) in LDS, A(kc) in regs
        if (kc < 3) {
            WSTAGE(kc + 1)
            LOADB(kc + 1, nh0, nl0, nh1, nl1)
        }
        MFMA_BLOCK(kc)
        if (kc < 3) { ah0 = nh0; al0 = nl0; ah1 = nh1; al1 = nl1; }
    }
    #undef LOADB
    EPILOGUE()
}

// ------- per-node aggregation: half-wave/node, tail-free, meta pipelined ---
// Edges are (src, npartial=dinv[src]); pads are (0, 0.0f) so NO masking.
// nv = npartial * dinv[node] (one mul, dv in register). Edge-meta for
// iteration j+1 prefetched before j's gathers (per-iter path = gather only).
// Self-loop term h[node]*dinv^2 computed here (load issued early).
__global__ __launch_bounds__(256) void agg_kernel(
    const unsigned short* __restrict__ H16, const int2* __restrict__ edges,
    const int* __restrict__ offsets, const float* __restrict__ dinv,
    const float* __restrict__ bias, const float* __restrict__ gate,
    float* __restrict__ outF, unsigned short* __restrict__ outH,
    unsigned short* __restrict__ outL, int M, int writeF32)
{
    int t = threadIdx.x;
    int hw = t >> 5;                  // half-wave 0..7
    int l32 = t & 31;
    int node = blockIdx.x * 8 + hw;
    if (node >= M) return;

    int beg = offsets[node];
    int end = offsets[node + 1];
    float dv = dinv[node];
    const unsigned short* __restrict__ Hc = H16 + l32 * 4;
    // self row: issue load early, consume after the gather loop
    ushort4 us = *(const ushort4*)(Hc + (size_t)node * D);
    float4 acc = make_float4(0.f, 0.f, 0.f, 0.f);

    int4 p0 = make_int4(0, 0, 0, 0), p1 = make_int4(0, 0, 0, 0);
    if (beg < end) {
        p0 = *(const int4*)(edges + beg);       // (s0,f0,s1,f1)
        p1 = *(const int4*)(edges + beg + 2);   // (s2,f2,s3,f3)
    }
    for (int j = beg; j < end; j += 4) {
        int jn = j + 4;
        int jp = (jn < end) ? jn : beg;         // clamped: always valid
        int4 q0 = *(const int4*)(edges + jp);
        int4 q1 = *(const int4*)(edges + jp + 2);
        ushort4 u0 = *(const ushort4*)(Hc + (size_t)p0.x * D);
        ushort4 u1 = *(const ushort4*)(Hc + (size_t)p0.z * D);
        ushort4 u2 = *(const ushort4*)(Hc + (size_t)p1.x * D);
        ushort4 u3 = *(const ushort4*)(Hc + (size_t)p1.z * D);
        float n0 = __int_as_float(p0.y) * dv, n1 = __int_as_float(p0.w) * dv;
        float n2 = __int_as_float(p1.y) * dv, n3 = __int_as_float(p1.w) * dv;
        acc.x = fmaf(h2f(u3.x), n3, fmaf(h2f(u2.x), n2, fmaf(h2f(u1.x), n1, fmaf(h2f(u0.x), n0, acc.x))));
        acc.y = fmaf(h2f(u3.y), n3, fmaf(h2f(u2.y), n2, fmaf(h2f(u1.y), n1, fmaf(h2f(u0.y), n0, acc.y))));
        acc.z = fmaf(h2f(u3.z), n3, fmaf(h2f(u2.z), n2, fmaf(h2f(u1.z), n1, fmaf(h2f(u0.z), n0, acc.z))));
        acc.w = fmaf(h2f(u3.w), n3, fmaf(h2f(u2.w), n2, fmaf(h2f(u1.w), n1, fmaf(h2f(u0.w), n0, acc.w))));
        p0 = q0; p1 = q1;
    }

    // self-loop term: norm = dinv^2 = 1/deg (exact, matches reference)
    float nself = dv * dv;
    acc.x = fmaf(h2f(us.x), nself, acc.x);
    acc.y = fmaf(h2f(us.y), nself, acc.y);
    acc.z = fmaf(h2f(us.z), nself, acc.z);
    acc.w = fmaf(h2f(us.w), nself, acc.w);

    float4 bv = *(const float4*)(bias + l32 * 4);
    float4 gv = *(const float4*)(gate + l32 * 4);
    acc.x = fmaxf(acc.x + bv.x, 0.f) * gv.x;
    acc.y = fmaxf(acc.y + bv.y, 0.f) * gv.y;
    acc.z = fmaxf(acc.z + bv.z, 0.f) * gv.z;
    acc.w = fmaxf(acc.w + bv.w, 0.f) * gv.w;

    if (writeF32) {
        *(float4*)(outF + (size_t)node * D + l32 * 4) = acc;
    } else {
        unsigned hx = bf16_rne(acc.x), hy = bf16_rne(acc.y);
        unsigned hz = bf16_rne(acc.z), hw4 = bf16_rne(acc.w);
        ushort4 hs = make_ushort4((unsigned short)hx, (unsigned short)hy,
                                  (unsigned short)hz, (unsigned short)hw4);
        ushort4 ls = make_ushort4(
            (unsigned short)bf16_rne(acc.x - __uint_as_float(hx << 16)),
            (unsigned short)bf16_rne(acc.y - __uint_as_float(hy << 16)),
            (unsigned short)bf16_rne(acc.z - __uint_as_float(hz << 16)),
            (unsigned short)bf16_rne(acc.w - __uint_as_float(hw4 << 16)));
        *(ushort4*)(outH + (size_t)node * D + l32 * 4) = hs;
        *(ushort4*)(outL + (size_t)node * D + l32 * 4) = ls;
    }
}

// ---------------------------------------------------------------------------
static inline size_t align_up(size_t v, size_t a) { return (v + a - 1) & ~(a - 1); }

extern "C" void kernel_launch(void* const* d_in, const int* in_sizes, int n_in,
                              void* d_out, int out_size, void* d_ws, size_t ws_size,
                              hipStream_t stream)
{
    const float* x   = (const float*)d_in[0];
    const int*   ei  = (const int*)d_in[1];   // int32 or int64 (auto-detected)
    const float* ts  = (const float*)d_in[2];
    const float* Wl[3] = { (const float*)d_in[3], (const float*)d_in[5], (const float*)d_in[7] };
    const float* bl[3] = { (const float*)d_in[4], (const float*)d_in[6], (const float*)d_in[8] };
    const float* Wg1 = (const float*)d_in[9];
    const float* bg1 = (const float*)d_in[10];
    const float* Wg2 = (const float*)d_in[11];
    const float* bg2 = (const float*)d_in[12];

    const int N = in_sizes[0] / D;      // 100000
    const int E = in_sizes[1] / 2;      // 600000
    const int NB = (N + SCHUNK - 1) / SCHUNK;   // scan blocks
    const size_t ECAP = (size_t)E + 3 * (size_t)N;  // padded CSR worst case

    // workspace carve (all 256B aligned)
    char* p = (char*)d_ws;
    unsigned short* h16 = (unsigned short*)p; p += align_up((size_t)N * D * 2, 256);
    unsigned short* xh  = (unsigned short*)p; p += align_up((size_t)N * D * 2, 256);
    unsigned short* xl  = (unsigned short*)p; p += align_up((size_t)N * D * 2, 256);
    int* src32  = (int*)p;   p += align_up((size_t)E * 4, 256);
    int* dst32  = (int*)p;   p += align_up((size_t)E * 4, 256);
    int* counts = (int*)p;   p += align_up((size_t)N * 4, 256);
    float* dinv = (float*)p; p += align_up((size_t)N * 4, 256);
    int* offs   = (int*)p;   p += align_up((size_t)(N + 1) * 4, 256);
    int* cursor = (int*)p;   p += align_up((size_t)N * 4, 256);
    int* edges4 = (int*)p;   p += align_up(ECAP * 4, 256);
    int2* edges8 = (int2*)p; p += align_up(ECAP * 8, 256);
    float* gate = (float*)p; p += align_up((size_t)D * 4, 256);
    int* bsums  = (int*)p;   p += align_up((size_t)NB * 4, 256);
    short8* Wf_hi = (short8*)p; p += align_up((size_t)3 * 2048 * 16, 256);
    short8* Wf_lo = (short8*)p; p += align_up((size_t)3 * 2048 * 16, 256);
    (void)ws_size; (void)n_in; (void)out_size;

    (void)hipMemsetAsync(counts, 0, (size_t)N * 4, stream);
    (void)hipMemsetAsync(edges4, 0xFF, ECAP * 4, stream);  // pad entries = -1

    int egrid = (E + 255) / 256;
    prep_kernel<<<25 + egrid, 256, 0, stream>>>(
        ei, src32, dst32, counts, E,
        Wl[0], Wl[1], Wl[2], Wf_hi, Wf_lo,
        ts, Wg1, bg1, Wg2, bg2, gate);
    scan_partial_kernel<<<NB, 256, 0, stream>>>(counts, bsums, N);
    scan_bsums_kernel<<<1, 1024, 0, stream>>>(bsums, offs + N, NB);
    scan_final_kernel<<<NB, 256, 0, stream>>>(counts, bsums, offs, cursor, dinv, N);
    bucket_kernel<<<egrid, 256, 0, stream>>>(src32, dst32, cursor, edges4, E);
    int xgrid = (int)((ECAP + 255) / 256);
    expand_kernel<<<xgrid, 256, 0, stream>>>(edges4, dinv, edges8, (int)ECAP);

    int ggrid = (N + GBM - 1) / GBM;
    int agrid = (N + 7) / 8;
    // layer 0: fp32 input
    gemm_f32_kernel<<<ggrid, 256, 0, stream>>>(x, Wf_hi, Wf_lo, h16, N);
    agg_kernel<<<agrid, 256, 0, stream>>>(h16, edges8, offs, dinv, bl[0], gate,
                                          nullptr, xh, xl, N, 0);
    // layer 1: bf16-plane input
    gemm_bf16_kernel<<<ggrid, 256, 0, stream>>>(xh, xl, Wf_hi + 2048, Wf_lo + 2048, h16, N);
    agg_kernel<<<agrid, 256, 0, stream>>>(h16, edges8, offs, dinv, bl[1], gate,
                                          nullptr, xh, xl, N, 0);
    // layer 2: bf16-plane input, fp32 output
    gemm_bf16_kernel<<<ggrid, 256, 0, stream>>>(xh, xl, Wf_hi + 4096, Wf_lo + 4096, h16, N);
    agg_kernel<<<agrid, 256, 0, stream>>>(h16, edges8, offs, dinv, bl[2], gate,
                                          (float*)d_out, nullptr, nullptr, N, 1);
}

// Round 8
// 240.831 us; speedup vs baseline: 1.1215x; 1.0785x over previous
//
#include <hip/hip_runtime.h>
#include <hip/hip_bf16.h>
#include <hip/hip_fp16.h>
#include <math.h>

// ---------------------------------------------------------------------------
// DynamicGCN: 3x (GCNConv -> ReLU -> *gate)
// R1: multi-block scan, hist fused into convert, dinv folded into scan C.
// R2: split-bf16 MFMA GEMM, W pre-swizzled into B-fragment order.
// R10: agg CSR padded to x4 (tail-free loop); self-edge folded into agg.
// R11: Wf staged per-kc into LDS (double-buffered); X loads global->reg;
//     agg half-wave/node, 4-deep, edge-meta software-pipelined.
// R12: bucket is throughput-bound on scattered partial-line HBM writes;
//     occupancy is NOT the limiter.
// R13: prep fusion KEPT; heterogeneous block-split fusion REVERTED.
// R14/R16: 4B bucket scatter + expand_kernel (edges8 = (src, dinv[src]),
//     pads (0,0)) -- norm recompute OFF agg's critical path. NOTE: 4B
//     payload did NOT shrink bucket WRITE_SIZE (each scattered store still
//     dirties a full 64B line); bucket ~38MB write is structural.
// R17: X round-trip halved: layers 1/2 use fp16 SINGLE-plane X with
//     fp16 hi/lo-split W via mfma_f32_16x16x32_f16 (2 MFMAs per frag vs 3).
//     X fp16 error (2^-12) is below H16's existing fp16 storage error.
//     Layer 0 (fp32 X, bf16-split W) and final fp32 output unchanged.
// ---------------------------------------------------------------------------

#define D 128   // feature dim (D_IN == HID == 128)

typedef __attribute__((ext_vector_type(8))) short short8;
typedef __attribute__((ext_vector_type(8))) _Float16 half8;
typedef __attribute__((ext_vector_type(4))) float floatx4;

__device__ __forceinline__ unsigned bf16_rne(float x) {
    unsigned u = __float_as_uint(x);
    return (u + 0x7FFFu + ((u >> 16) & 1u)) >> 16;
}

__device__ __forceinline__ void gload_lds16(const void* g, void* l) {
    __builtin_amdgcn_global_load_lds(
        (const __attribute__((address_space(1))) unsigned int*)g,
        (__attribute__((address_space(3))) unsigned int*)l, 16, 0, 0);
}

__device__ __forceinline__ float h2f(unsigned short u) {
    return __half2float(__ushort_as_half(u));
}

// ---- prep: W swizzle (blocks 0..23) + gate MLP (24) + edge convert (25..) -
// Layer 0 fragments: bf16 hi/lo split. Layers 1/2: fp16 hi/lo split.
__global__ __launch_bounds__(256) void prep_kernel(
    const int* __restrict__ w, int* __restrict__ src32,
    int* __restrict__ dst32, int* __restrict__ counts, int E,
    const float* __restrict__ W0, const float* __restrict__ W1,
    const float* __restrict__ W2, short8* __restrict__ Wf_hi,
    short8* __restrict__ Wf_lo,
    const float* __restrict__ t, const float* __restrict__ Wg1,
    const float* __restrict__ bg1, const float* __restrict__ Wg2,
    const float* __restrict__ bg2, float* __restrict__ gate)
{
    int b = blockIdx.x;
    if (b < 24) {
        int f = b * 256 + threadIdx.x;   // 0..6143
        int layer = f >> 11;
        int fi = f & 2047;
        int lane = fi & 63;
        int tt = fi >> 6;                // kc*8 + n
        int kc = tt >> 3, n = tt & 7;
        const float* W = (layer == 0) ? W0 : (layer == 1) ? W1 : W2;
        int krow = kc * 32 + (lane >> 4) * 8;
        int col = n * 16 + (lane & 15);
        short8 hv, lv;
        if (layer == 0) {
            #pragma unroll
            for (int j = 0; j < 8; j++) {
                float x = W[(size_t)(krow + j) * D + col];
                unsigned hb = bf16_rne(x);
                float hf = __uint_as_float(hb << 16);
                unsigned lb = bf16_rne(x - hf);
                hv[j] = (short)hb;
                lv[j] = (short)lb;
            }
        } else {
            #pragma unroll
            for (int j = 0; j < 8; j++) {
                float x = W[(size_t)(krow + j) * D + col];
                __half hh = __float2half(x);
                float hf = __half2float(hh);
                __half ll = __float2half(x - hf);
                hv[j] = (short)__half_as_ushort(hh);
                lv[j] = (short)__half_as_ushort(ll);
            }
        }
        Wf_hi[f] = hv;
        Wf_lo[f] = lv;
        return;
    }
    if (b == 24) {
        __shared__ float u[D];
        int j = threadIdx.x;
        if (j < D) {
            float tv = t[0];
            u[j] = tanhf(tv * Wg1[j] + bg1[j]);
        }
        __syncthreads();
        if (j < D) {
            float s = bg2[j];
            #pragma unroll 8
            for (int k = 0; k < D; k++) s += u[k] * Wg2[k * D + j];
            gate[j] = 1.0f / (1.0f + expf(-s));
        }
        return;
    }
    // ---- edge convert (int64 auto-detect) + fused degree histogram ----
    __shared__ int flag;
    if (threadIdx.x == 0) {
        int z = 0;
        for (int k = 0; k < 64; k++) z |= w[2 * k + 1];
        flag = (z == 0) ? 1 : 0;   // all odd words zero => int64 layout
    }
    __syncthreads();
    int i64 = flag;
    int e = (b - 25) * 256 + threadIdx.x;
    if (e >= E) return;
    int s = i64 ? w[2 * e] : w[e];                       // little-endian low word
    int d = i64 ? w[2 * (E + e)] : w[E + e];
    src32[e] = s;
    dst32[e] = d;
    atomicAdd(&counts[d], 1);
}

// ------------------- multi-block exclusive scan ----------------------------
#define SCHUNK 1024
__device__ __forceinline__ int cap4(int c) { return (c + 3) & ~3; }

__global__ __launch_bounds__(256) void scan_partial_kernel(
    const int* __restrict__ counts, int* __restrict__ bsums, int N)
{
    int base = blockIdx.x * SCHUNK + threadIdx.x * 4;
    int s = 0;
    if (base + 3 < N) {
        int4 v = *(const int4*)(counts + base);
        s = cap4(v.x) + cap4(v.y) + cap4(v.z) + cap4(v.w);
    } else {
        for (int k = 0; k < 4; k++) if (base + k < N) s += cap4(counts[base + k]);
    }
    #pragma unroll
    for (int off = 1; off < 64; off <<= 1) s += __shfl_xor(s, off);
    __shared__ int wsum[4];
    int lane = threadIdx.x & 63, wid = threadIdx.x >> 6;
    if (lane == 0) wsum[wid] = s;
    __syncthreads();
    if (threadIdx.x == 0)
        bsums[blockIdx.x] = wsum[0] + wsum[1] + wsum[2] + wsum[3];
}

__global__ __launch_bounds__(1024) void scan_bsums_kernel(
    int* __restrict__ bsums, int* __restrict__ total_out, int B)
{
    int t = threadIdx.x;
    int v = (t < B) ? bsums[t] : 0;
    int lane = t & 63, wid = t >> 6;
    int s = v;
    #pragma unroll
    for (int off = 1; off < 64; off <<= 1) {
        int n = __shfl_up(s, off);
        if (lane >= off) s += n;
    }
    __shared__ int wsum[16], wpre[16];
    if (lane == 63) wsum[wid] = s;
    __syncthreads();
    if (t < 16) {
        int ws = wsum[t];
        #pragma unroll
        for (int off = 1; off < 16; off <<= 1) {
            int n = __shfl_up(ws, off);
            if (t >= off) ws += n;
        }
        wpre[t] = ws;
    }
    __syncthreads();
    int wex = wid ? wpre[wid - 1] : 0;
    if (t < B) bsums[t] = wex + (s - v);      // exclusive
    if (t == 0) *total_out = wpre[15];        // grand total -> offsets[N]
}

__global__ __launch_bounds__(256) void scan_final_kernel(
    const int* __restrict__ counts, const int* __restrict__ bsums,
    int* __restrict__ offsets, int* __restrict__ cursor,
    float* __restrict__ dinv, int N)
{
    int base = blockIdx.x * SCHUNK + threadIdx.x * 4;
    int c[4];
    float dd[4];
    bool full = (base + 3 < N);
    if (full) {
        int4 v = *(const int4*)(counts + base);
        c[0] = cap4(v.x); c[1] = cap4(v.y); c[2] = cap4(v.z); c[3] = cap4(v.w);
        dd[0] = rsqrtf((float)(v.x + 1)); dd[1] = rsqrtf((float)(v.y + 1));
        dd[2] = rsqrtf((float)(v.z + 1)); dd[3] = rsqrtf((float)(v.w + 1));
    } else {
        for (int k = 0; k < 4; k++) {
            int r = (base + k < N) ? counts[base + k] : 0;
            c[k] = (base + k < N) ? cap4(r) : 0;
            dd[k] = rsqrtf((float)(r + 1));
        }
    }
    int sum = c[0] + c[1] + c[2] + c[3];
    int lane = threadIdx.x & 63, wid = threadIdx.x >> 6;
    int s = sum;
    #pragma unroll
    for (int off = 1; off < 64; off <<= 1) {
        int n = __shfl_up(s, off);
        if (lane >= off) s += n;
    }
    __shared__ int wsum[4], wpre[4];
    if (lane == 63) wsum[wid] = s;
    __syncthreads();
    if (threadIdx.x == 0) {
        int a = 0;
        #pragma unroll
        for (int k = 0; k < 4; k++) { wpre[k] = a; a += wsum[k]; }
    }
    __syncthreads();
    int e0 = bsums[blockIdx.x] + wpre[wid] + (s - sum);
    int4 o = make_int4(e0, e0 + c[0], e0 + c[0] + c[1], e0 + c[0] + c[1] + c[2]);
    float4 dv = make_float4(dd[0], dd[1], dd[2], dd[3]);
    if (full) {
        *(int4*)(offsets + base) = o;
        *(int4*)(cursor + base) = o;
        *(float4*)(dinv + base) = dv;
    } else {
        int oo[4] = { o.x, o.y, o.z, o.w };
        for (int k = 0; k < 4; k++)
            if (base + k < N) {
                offsets[base + k] = oo[k];
                cursor[base + k] = oo[k];
                dinv[base + k] = dd[k];
            }
    }
}

// ---------- bucket edges by dst (CSR, 4B src-only payload) -----------------
__global__ __launch_bounds__(256) void bucket_kernel(
    const int* __restrict__ src32, const int* __restrict__ dst32,
    int* __restrict__ cursor, int* __restrict__ edges4, int E)
{
    int e = blockIdx.x * blockDim.x + threadIdx.x;
    if (e >= E) return;
    int s = src32[e];
    int d = dst32[e];
    int pos = atomicAdd(&cursor[d], 1);
    edges4[pos] = s;
}

// ---------- expand: edges4 -> edges8 = (src, dinv[src]); pads -> (0,0) -----
__global__ __launch_bounds__(256) void expand_kernel(
    const int* __restrict__ edges4, const float* __restrict__ dinv,
    int2* __restrict__ edges8, int cap)
{
    int i = blockIdx.x * blockDim.x + threadIdx.x;
    if (i >= cap) return;
    int s = edges4[i];
    int ss = (s < 0) ? 0 : s;
    float f = (s < 0) ? 0.f : dinv[ss];
    edges8[i] = make_int2(ss, __float_as_int(f));
}

// ----- cooperative Wf stage: 16KB (hi 8KB + lo 8KB) per kc into LDS --------
#define WSTAGE(kc_)                                                           \
    {                                                                         \
        short* wb_ = Wfs + (((kc_) & 1) ? 8192 : 0);                          \
        const short8* gh_ = Wf_hi + (size_t)(kc_) * 512;                      \
        const short8* gl_ = Wf_lo + (size_t)(kc_) * 512;                      \
        _Pragma("unroll")                                                     \
        for (int i_ = 0; i_ < 2; i_++) {                                      \
            int c_ = i_ * 256 + w * 64;                                       \
            gload_lds16(gh_ + c_ + lane, wb_ + c_ * 8);                       \
            gload_lds16(gl_ + c_ + lane, wb_ + 4096 + c_ * 8);                \
        }                                                                     \
    }

// ------------- bf16 split MFMA inner block (layer 0) -----------------------
#define MFMA_BLOCK(kc)                                                        \
    {                                                                         \
        const short* wb = Wfs + (((kc) & 1) ? 8192 : 0);                      \
        _Pragma("unroll")                                                     \
        for (int n = 0; n < 8; n++) {                                         \
            short8 bh = *(const short8*)(wb + (n * 64 + lane) * 8);           \
            short8 bl = *(const short8*)(wb + 4096 + (n * 64 + lane) * 8);    \
            acc[0][n] = __builtin_amdgcn_mfma_f32_16x16x32_bf16(ah0, bh, acc[0][n], 0, 0, 0); \
            acc[0][n] = __builtin_amdgcn_mfma_f32_16x16x32_bf16(ah0, bl, acc[0][n], 0, 0, 0); \
            acc[0][n] = __builtin_amdgcn_mfma_f32_16x16x32_bf16(al0, bh, acc[0][n], 0, 0, 0); \
            acc[1][n] = __builtin_amdgcn_mfma_f32_16x16x32_bf16(ah1, bh, acc[1][n], 0, 0, 0); \
            acc[1][n] = __builtin_amdgcn_mfma_f32_16x16x32_bf16(ah1, bl, acc[1][n], 0, 0, 0); \
            acc[1][n] = __builtin_amdgcn_mfma_f32_16x16x32_bf16(al1, bh, acc[1][n], 0, 0, 0); \
        }                                                                     \
    }

// ------------- fp16 split-W MFMA inner block (layers 1/2) ------------------
// A = X fp16 single plane; B = W fp16 hi + lo (w = wh + wl, ~22-bit W).
#define MFMA_BLOCK_F16(kc)                                                    \
    {                                                                         \
        const short* wb = Wfs + (((kc) & 1) ? 8192 : 0);                      \
        _Pragma("unroll")                                                     \
        for (int n = 0; n < 8; n++) {                                         \
            half8 bh = *(const half8*)(wb + (n * 64 + lane) * 8);             \
            half8 bl = *(const half8*)(wb + 4096 + (n * 64 + lane) * 8);      \
            acc[0][n] = __builtin_amdgcn_mfma_f32_16x16x32_f16(ah0, bh, acc[0][n], 0, 0, 0); \
            acc[0][n] = __builtin_amdgcn_mfma_f32_16x16x32_f16(ah0, bl, acc[0][n], 0, 0, 0); \
            acc[1][n] = __builtin_amdgcn_mfma_f32_16x16x32_f16(ah1, bh, acc[1][n], 0, 0, 0); \
            acc[1][n] = __builtin_amdgcn_mfma_f32_16x16x32_f16(ah1, bl, acc[1][n], 0, 0, 0); \
        }                                                                     \
    }

#define EPILOGUE()                                                            \
    _Pragma("unroll")                                                         \
    for (int rt = 0; rt < 2; rt++) {                                          \
        _Pragma("unroll")                                                     \
        for (int reg = 0; reg < 4; reg++) {                                   \
            int row = rowbase + rt * 16 + qd * 4 + reg;                       \
            if (row < M) {                                                    \
                unsigned short* hp = H16 + (size_t)row * D + m16;             \
                _Pragma("unroll")                                             \
                for (int n = 0; n < 8; n++)                                   \
                    hp[n * 16] = __half_as_ushort(__float2half(acc[rt][n][reg])); \
            }                                                                 \
        }                                                                     \
    }

// ------------- GEMM variant A: fp32 X input (layer 0 only) -----------------
#define GBM 128
__device__ __forceinline__ void cvt8(const float* f, short8& hi, short8& lo) {
    #pragma unroll
    for (int j = 0; j < 8; j++) {
        unsigned hb = bf16_rne(f[j]);
        float hf = __uint_as_float(hb << 16);
        unsigned lb = bf16_rne(f[j] - hf);
        hi[j] = (short)hb;
        lo[j] = (short)lb;
    }
}

__global__ __launch_bounds__(256) void gemm_f32_kernel(
    const float* __restrict__ X, const short8* __restrict__ Wf_hi,
    const short8* __restrict__ Wf_lo, unsigned short* __restrict__ H16, int M)
{
    __shared__ short Wfs[16384];   // 32KB: 2 bufs x (hi 8KB + lo 8KB)
    int tid = threadIdx.x;
    int w = tid >> 6, lane = tid & 63;
    int m16 = lane & 15, qd = lane >> 4;
    int rowbase = blockIdx.x * GBM + w * 32;

    int r0 = rowbase + m16;      if (r0 >= M) r0 = M - 1;
    int r1 = rowbase + m16 + 16; if (r1 >= M) r1 = M - 1;
    const float* xp0 = X + (size_t)r0 * D + qd * 8;
    const float* xp1 = X + (size_t)r1 * D + qd * 8;

    floatx4 acc[2][8];
    #pragma unroll
    for (int rt = 0; rt < 2; rt++)
        #pragma unroll
        for (int n = 0; n < 8; n++)
            acc[rt][n] = (floatx4)(0.f);

    #define LOADA(kc_, A0, A1)                                              \
        {                                                                   \
            *(float4*)(A0)     = *(const float4*)(xp0 + (kc_) * 32);        \
            *(float4*)(A0 + 4) = *(const float4*)(xp0 + (kc_) * 32 + 4);    \
            *(float4*)(A1)     = *(const float4*)(xp1 + (kc_) * 32);        \
            *(float4*)(A1 + 4) = *(const float4*)(xp1 + (kc_) * 32 + 4);    \
        }

    float a0c[8], a1c[8], a0n[8], a1n[8];
    WSTAGE(0)
    LOADA(0, a0c, a1c)

    #pragma unroll
    for (int kc = 0; kc < 4; kc++) {
        __syncthreads();     // drains vmcnt: Wf(kc) in LDS, A(kc) in regs
        if (kc < 3) {
            WSTAGE(kc + 1)
            LOADA(kc + 1, a0n, a1n)
        }
        short8 ah0, al0, ah1, al1;
        cvt8(a0c, ah0, al0);
        cvt8(a1c, ah1, al1);
        MFMA_BLOCK(kc)
        if (kc < 3) {
            #pragma unroll
            for (int z = 0; z < 8; z++) { a0c[z] = a0n[z]; a1c[z] = a1n[z]; }
        }
    }
    #undef LOADA
    EPILOGUE()
}

// ------ GEMM variant B: fp16 single-plane X input (layers 1,2) -------------
__global__ __launch_bounds__(256) void gemm_f16_kernel(
    const unsigned short* __restrict__ Xh,
    const short8* __restrict__ Wf_hi, const short8* __restrict__ Wf_lo,
    unsigned short* __restrict__ H16, int M)
{
    __shared__ short Wfs[16384];   // 32KB: 2 bufs x (hi 8KB + lo 8KB)
    int tid = threadIdx.x;
    int w = tid >> 6, lane = tid & 63;
    int m16 = lane & 15, qd = lane >> 4;
    int rowbase = blockIdx.x * GBM + w * 32;

    int r0 = rowbase + m16;      if (r0 >= M) r0 = M - 1;
    int r1 = rowbase + m16 + 16; if (r1 >= M) r1 = M - 1;
    const unsigned short* xh0 = Xh + (size_t)r0 * D + qd * 8;
    const unsigned short* xh1 = Xh + (size_t)r1 * D + qd * 8;

    floatx4 acc[2][8];
    #pragma unroll
    for (int rt = 0; rt < 2; rt++)
        #pragma unroll
        for (int n = 0; n < 8; n++)
            acc[rt][n] = (floatx4)(0.f);

    half8 ah0, ah1, nh0, nh1;
    WSTAGE(0)
    ah0 = *(const half8*)(xh0);
    ah1 = *(const half8*)(xh1);

    #pragma unroll
    for (int kc = 0; kc < 4; kc++) {
        __syncthreads();     // drains vmcnt: Wf(kc) in LDS, A(kc) in regs
        if (kc < 3) {
            WSTAGE(kc + 1)
            nh0 = *(const half8*)(xh0 + (kc + 1) * 32);
            nh1 = *(const half8*)(xh1 + (kc + 1) * 32);
        }
        MFMA_BLOCK_F16(kc)
        if (kc < 3) { ah0 = nh0; ah1 = nh1; }
    }
    EPILOGUE()
}

// ------- per-node aggregation: half-wave/node, tail-free, meta pipelined ---
// Edges are (src, npartial=dinv[src]); pads are (0, 0.0f) so NO masking.
// nv = npartial * dinv[node]. Non-final layers write a SINGLE fp16 plane.
__global__ __launch_bounds__(256) void agg_kernel(
    const unsigned short* __restrict__ H16, const int2* __restrict__ edges,
    const int* __restrict__ offsets, const float* __restrict__ dinv,
    const float* __restrict__ bias, const float* __restrict__ gate,
    float* __restrict__ outF, unsigned short* __restrict__ outH,
    int M, int writeF32)
{
    int t = threadIdx.x;
    int hw = t >> 5;                  // half-wave 0..7
    int l32 = t & 31;
    int node = blockIdx.x * 8 + hw;
    if (node >= M) return;

    int beg = offsets[node];
    int end = offsets[node + 1];
    float dv = dinv[node];
    const unsigned short* __restrict__ Hc = H16 + l32 * 4;
    // self row: issue load early, consume after the gather loop
    ushort4 us = *(const ushort4*)(Hc + (size_t)node * D);
    float4 acc = make_float4(0.f, 0.f, 0.f, 0.f);

    int4 p0 = make_int4(0, 0, 0, 0), p1 = make_int4(0, 0, 0, 0);
    if (beg < end) {
        p0 = *(const int4*)(edges + beg);       // (s0,f0,s1,f1)
        p1 = *(const int4*)(edges + beg + 2);   // (s2,f2,s3,f3)
    }
    for (int j = beg; j < end; j += 4) {
        int jn = j + 4;
        int jp = (jn < end) ? jn : beg;         // clamped: always valid
        int4 q0 = *(const int4*)(edges + jp);
        int4 q1 = *(const int4*)(edges + jp + 2);
        ushort4 u0 = *(const ushort4*)(Hc + (size_t)p0.x * D);
        ushort4 u1 = *(const ushort4*)(Hc + (size_t)p0.z * D);
        ushort4 u2 = *(const ushort4*)(Hc + (size_t)p1.x * D);
        ushort4 u3 = *(const ushort4*)(Hc + (size_t)p1.z * D);
        float n0 = __int_as_float(p0.y) * dv, n1 = __int_as_float(p0.w) * dv;
        float n2 = __int_as_float(p1.y) * dv, n3 = __int_as_float(p1.w) * dv;
        acc.x = fmaf(h2f(u3.x), n3, fmaf(h2f(u2.x), n2, fmaf(h2f(u1.x), n1, fmaf(h2f(u0.x), n0, acc.x))));
        acc.y = fmaf(h2f(u3.y), n3, fmaf(h2f(u2.y), n2, fmaf(h2f(u1.y), n1, fmaf(h2f(u0.y), n0, acc.y))));
        acc.z = fmaf(h2f(u3.z), n3, fmaf(h2f(u2.z), n2, fmaf(h2f(u1.z), n1, fmaf(h2f(u0.z), n0, acc.z))));
        acc.w = fmaf(h2f(u3.w), n3, fmaf(h2f(u2.w), n2, fmaf(h2f(u1.w), n1, fmaf(h2f(u0.w), n0, acc.w))));
        p0 = q0; p1 = q1;
    }

    // self-loop term: norm = dinv^2 = 1/deg (exact, matches reference)
    float nself = dv * dv;
    acc.x = fmaf(h2f(us.x), nself, acc.x);
    acc.y = fmaf(h2f(us.y), nself, acc.y);
    acc.z = fmaf(h2f(us.z), nself, acc.z);
    acc.w = fmaf(h2f(us.w), nself, acc.w);

    float4 bv = *(const float4*)(bias + l32 * 4);
    float4 gv = *(const float4*)(gate + l32 * 4);
    acc.x = fmaxf(acc.x + bv.x, 0.f) * gv.x;
    acc.y = fmaxf(acc.y + bv.y, 0.f) * gv.y;
    acc.z = fmaxf(acc.z + bv.z, 0.f) * gv.z;
    acc.w = fmaxf(acc.w + bv.w, 0.f) * gv.w;

    if (writeF32) {
        *(float4*)(outF + (size_t)node * D + l32 * 4) = acc;
    } else {
        ushort4 hs = make_ushort4(
            __half_as_ushort(__float2half(acc.x)),
            __half_as_ushort(__float2half(acc.y)),
            __half_as_ushort(__float2half(acc.z)),
            __half_as_ushort(__float2half(acc.w)));
        *(ushort4*)(outH + (size_t)node * D + l32 * 4) = hs;
    }
}

// ---------------------------------------------------------------------------
static inline size_t align_up(size_t v, size_t a) { return (v + a - 1) & ~(a - 1); }

extern "C" void kernel_launch(void* const* d_in, const int* in_sizes, int n_in,
                              void* d_out, int out_size, void* d_ws, size_t ws_size,
                              hipStream_t stream)
{
    const float* x   = (const float*)d_in[0];
    const int*   ei  = (const int*)d_in[1];   // int32 or int64 (auto-detected)
    const float* ts  = (const float*)d_in[2];
    const float* Wl[3] = { (const float*)d_in[3], (const float*)d_in[5], (const float*)d_in[7] };
    const float* bl[3] = { (const float*)d_in[4], (const float*)d_in[6], (const float*)d_in[8] };
    const float* Wg1 = (const float*)d_in[9];
    const float* bg1 = (const float*)d_in[10];
    const float* Wg2 = (const float*)d_in[11];
    const float* bg2 = (const float*)d_in[12];

    const int N = in_sizes[0] / D;      // 100000
    const int E = in_sizes[1] / 2;      // 600000
    const int NB = (N + SCHUNK - 1) / SCHUNK;   // scan blocks
    const size_t ECAP = (size_t)E + 3 * (size_t)N;  // padded CSR worst case

    // workspace carve (all 256B aligned)
    char* p = (char*)d_ws;
    unsigned short* h16 = (unsigned short*)p; p += align_up((size_t)N * D * 2, 256);
    unsigned short* xh  = (unsigned short*)p; p += align_up((size_t)N * D * 2, 256);
    int* src32  = (int*)p;   p += align_up((size_t)E * 4, 256);
    int* dst32  = (int*)p;   p += align_up((size_t)E * 4, 256);
    int* counts = (int*)p;   p += align_up((size_t)N * 4, 256);
    float* dinv = (float*)p; p += align_up((size_t)N * 4, 256);
    int* offs   = (int*)p;   p += align_up((size_t)(N + 1) * 4, 256);
    int* cursor = (int*)p;   p += align_up((size_t)N * 4, 256);
    int* edges4 = (int*)p;   p += align_up(ECAP * 4, 256);
    int2* edges8 = (int2*)p; p += align_up(ECAP * 8, 256);
    float* gate = (float*)p; p += align_up((size_t)D * 4, 256);
    int* bsums  = (int*)p;   p += align_up((size_t)NB * 4, 256);
    short8* Wf_hi = (short8*)p; p += align_up((size_t)3 * 2048 * 16, 256);
    short8* Wf_lo = (short8*)p; p += align_up((size_t)3 * 2048 * 16, 256);
    (void)ws_size; (void)n_in; (void)out_size;

    (void)hipMemsetAsync(counts, 0, (size_t)N * 4, stream);
    (void)hipMemsetAsync(edges4, 0xFF, ECAP * 4, stream);  // pad entries = -1

    int egrid = (E + 255) / 256;
    prep_kernel<<<25 + egrid, 256, 0, stream>>>(
        ei, src32, dst32, counts, E,
        Wl[0], Wl[1], Wl[2], Wf_hi, Wf_lo,
        ts, Wg1, bg1, Wg2, bg2, gate);
    scan_partial_kernel<<<NB, 256, 0, stream>>>(counts, bsums, N);
    scan_bsums_kernel<<<1, 1024, 0, stream>>>(bsums, offs + N, NB);
    scan_final_kernel<<<NB, 256, 0, stream>>>(counts, bsums, offs, cursor, dinv, N);
    bucket_kernel<<<egrid, 256, 0, stream>>>(src32, dst32, cursor, edges4, E);
    int xgrid = (int)((ECAP + 255) / 256);
    expand_kernel<<<xgrid, 256, 0, stream>>>(edges4, dinv, edges8, (int)ECAP);

    int ggrid = (N + GBM - 1) / GBM;
    int agrid = (N + 7) / 8;
    // layer 0: fp32 input, bf16-split path
    gemm_f32_kernel<<<ggrid, 256, 0, stream>>>(x, Wf_hi, Wf_lo, h16, N);
    agg_kernel<<<agrid, 256, 0, stream>>>(h16, edges8, offs, dinv, bl[0], gate,
                                          nullptr, xh, N, 0);
    // layer 1: fp16 single-plane input, fp16 split-W MFMA
    gemm_f16_kernel<<<ggrid, 256, 0, stream>>>(xh, Wf_hi + 2048, Wf_lo + 2048, h16, N);
    agg_kernel<<<agrid, 256, 0, stream>>>(h16, edges8, offs, dinv, bl[1], gate,
                                          nullptr, xh, N, 0);
    // layer 2: fp16 single-plane input, fp32 output
    gemm_f16_kernel<<<ggrid, 256, 0, stream>>>(xh, Wf_hi + 4096, Wf_lo + 4096, h16, N);
    agg_kernel<<<agrid, 256, 0, stream>>>(h16, edges8, offs, dinv, bl[2], gate,
                                          (float*)d_out, nullptr, N, 1);
}